// Round 1
// baseline (1394.730 us; speedup 1.0000x reference)
//
#include <hip/hip_runtime.h>

typedef __bf16 bf16;
typedef __bf16 bf16x4 __attribute__((ext_vector_type(4)));
typedef __bf16 bf16x8 __attribute__((ext_vector_type(8)));
typedef float f32x4 __attribute__((ext_vector_type(4)));

#define N_NODES 1568
#define CDIM 2048

// ---------------- async global->LDS 16B ----------------
__device__ __forceinline__ void async_copy16(const bf16* g, bf16* l) {
    __builtin_amdgcn_global_load_lds(
        (const __attribute__((address_space(1))) unsigned int*)g,
        (__attribute__((address_space(3))) unsigned int*)l, 16, 0, 0);
}

// ---------------- generic NT bf16 MFMA GEMM ----------------
// C[M,N] = A[M,K] * B[N,K]^T ; lda=ldb=K, ldc=N. Batched via grid.z with strides.
template <typename OUT_T>
__global__ __launch_bounds__(256) void gemm_nt(const bf16* __restrict__ A,
                                               const bf16* __restrict__ B,
                                               OUT_T* __restrict__ C,
                                               int M, int N, int K,
                                               long sAb, long sBb, long sCb) {
    __shared__ __align__(16) bf16 sA[128 * 32];
    __shared__ __align__(16) bf16 sB[128 * 32];
    const int bz = blockIdx.z;
    A += (long)bz * sAb; B += (long)bz * sBb; C += (long)bz * sCb;
    const int m0 = blockIdx.x * 128, n0 = blockIdx.y * 128;
    const int t = threadIdx.x;
    const int lane = t & 63, wave = t >> 6;
    const int wr = wave >> 1, wc = wave & 1;
    const int l15 = lane & 15, quad = lane >> 4;

    f32x4 acc[4][4];
#pragma unroll
    for (int i = 0; i < 4; i++)
#pragma unroll
        for (int j = 0; j < 4; j++) acc[i][j] = (f32x4){0.f, 0.f, 0.f, 0.f};

    // staging chunks: chunk c (0..511) covers LDS bytes [c*16, c*16+16),
    // global row = c>>2, col elems = (c&3)*8. Thread t handles c=t and c=t+256.
    const int ko = (t & 3) * 8;
    int ra1 = m0 + (t >> 2);          if (ra1 >= M) ra1 = M - 1;
    int ra2 = m0 + ((t + 256) >> 2);  if (ra2 >= M) ra2 = M - 1;
    int rb1 = n0 + (t >> 2);          if (rb1 >= N) rb1 = N - 1;
    int rb2 = n0 + ((t + 256) >> 2);  if (rb2 >= N) rb2 = N - 1;
    const bf16* gA1 = A + (long)ra1 * K + ko;
    const bf16* gA2 = A + (long)ra2 * K + ko;
    const bf16* gB1 = B + (long)rb1 * K + ko;
    const bf16* gB2 = B + (long)rb2 * K + ko;
    bf16* lA1 = sA + t * 8;  bf16* lA2 = sA + (t + 256) * 8;
    bf16* lB1 = sB + t * 8;  bf16* lB2 = sB + (t + 256) * 8;

    for (int k0 = 0; k0 < K; k0 += 32) {
        __syncthreads();
        async_copy16(gA1 + k0, lA1);
        async_copy16(gA2 + k0, lA2);
        async_copy16(gB1 + k0, lB1);
        async_copy16(gB2 + k0, lB2);
        __syncthreads();
        bf16x8 af[4], bfr[4];
#pragma unroll
        for (int i = 0; i < 4; i++)
            af[i] = *(const bf16x8*)(sA + (wr * 64 + i * 16 + l15) * 32 + quad * 8);
#pragma unroll
        for (int j = 0; j < 4; j++)
            bfr[j] = *(const bf16x8*)(sB + (wc * 64 + j * 16 + l15) * 32 + quad * 8);
#pragma unroll
        for (int i = 0; i < 4; i++)
#pragma unroll
            for (int j = 0; j < 4; j++)
                acc[i][j] = __builtin_amdgcn_mfma_f32_16x16x32_bf16(af[i], bfr[j], acc[i][j], 0, 0, 0);
    }
    // epilogue: D[row=quad*4+r][col=l15] per 16x16 tile (m89-verified layout)
#pragma unroll
    for (int i = 0; i < 4; i++) {
        const int row0 = m0 + wr * 64 + i * 16 + quad * 4;
#pragma unroll
        for (int j = 0; j < 4; j++) {
            const int col = n0 + wc * 64 + j * 16 + l15;
            if (col < N) {
#pragma unroll
                for (int r = 0; r < 4; r++) {
                    const int row = row0 + r;
                    if (row < M) C[(long)row * N + col] = (OUT_T)acc[i][j][r];
                }
            }
        }
    }
}

// ---------------- deconv grouped GEMM ----------------
// grid.z = b*9 + g, g = kh*3+kw. A = Wt[g][1024][2048], B rows = u pixels.
// out[b][oc][oh][ow], oh = 3*ih + (1-kh), ow = 3*iw + (1-kw).
__global__ __launch_bounds__(256) void deconv_gemm(const bf16* __restrict__ Wt,
                                                   const bf16* __restrict__ u,
                                                   const float* __restrict__ db,
                                                   float* __restrict__ out) {
    const int gz = blockIdx.z;
    const int b = gz / 9, g = gz % 9;
    const int kh = g / 3, kw = g % 3;
    const int nh = (kh == 1) ? 28 : 27, nw = (kw == 1) ? 28 : 27;
    const int ihlo = (kh == 2) ? 1 : 0, iwlo = (kw == 2) ? 1 : 0;
    const int dh = 1 - kh, dw = 1 - kw;
    const int Ng = nh * nw;
    const int m0 = blockIdx.x * 128, n0 = blockIdx.y * 128;
    if (n0 >= Ng) return;
    __shared__ __align__(16) bf16 sA[128 * 32];
    __shared__ __align__(16) bf16 sB[128 * 32];
    const bf16* A = Wt + (long)g * 1024 * 2048;
    const bf16* B = u + (long)b * 784 * 2048;
    const int t = threadIdx.x;
    const int lane = t & 63, wave = t >> 6;
    const int wr = wave >> 1, wc = wave & 1;
    const int l15 = lane & 15, quad = lane >> 4;

    f32x4 acc[4][4];
#pragma unroll
    for (int i = 0; i < 4; i++)
#pragma unroll
        for (int j = 0; j < 4; j++) acc[i][j] = (f32x4){0.f, 0.f, 0.f, 0.f};

    const int ko = (t & 3) * 8;
    const int rA1 = m0 + (t >> 2);          // M=1024, exact tiles, no clamp
    const int rA2 = m0 + ((t + 256) >> 2);
    int p1 = n0 + (t >> 2);          if (p1 >= Ng) p1 = Ng - 1;
    int p2 = n0 + ((t + 256) >> 2);  if (p2 >= Ng) p2 = Ng - 1;
    const int ih1 = ihlo + p1 / nw, iw1 = iwlo + p1 % nw;
    const int ih2 = ihlo + p2 / nw, iw2 = iwlo + p2 % nw;
    const bf16* gA1 = A + (long)rA1 * 2048 + ko;
    const bf16* gA2 = A + (long)rA2 * 2048 + ko;
    const bf16* gB1 = B + ((long)ih1 * 28 + iw1) * 2048 + ko;
    const bf16* gB2 = B + ((long)ih2 * 28 + iw2) * 2048 + ko;
    bf16* lA1 = sA + t * 8;  bf16* lA2 = sA + (t + 256) * 8;
    bf16* lB1 = sB + t * 8;  bf16* lB2 = sB + (t + 256) * 8;

    for (int k0 = 0; k0 < 2048; k0 += 32) {
        __syncthreads();
        async_copy16(gA1 + k0, lA1);
        async_copy16(gA2 + k0, lA2);
        async_copy16(gB1 + k0, lB1);
        async_copy16(gB2 + k0, lB2);
        __syncthreads();
        bf16x8 af[4], bfr[4];
#pragma unroll
        for (int i = 0; i < 4; i++)
            af[i] = *(const bf16x8*)(sA + (wr * 64 + i * 16 + l15) * 32 + quad * 8);
#pragma unroll
        for (int j = 0; j < 4; j++)
            bfr[j] = *(const bf16x8*)(sB + (wc * 64 + j * 16 + l15) * 32 + quad * 8);
#pragma unroll
        for (int i = 0; i < 4; i++)
#pragma unroll
            for (int j = 0; j < 4; j++)
                acc[i][j] = __builtin_amdgcn_mfma_f32_16x16x32_bf16(af[i], bfr[j], acc[i][j], 0, 0, 0);
    }
#pragma unroll
    for (int i = 0; i < 4; i++) {
        const int oc0 = m0 + wr * 64 + i * 16 + quad * 4;
#pragma unroll
        for (int j = 0; j < 4; j++) {
            const int p = n0 + wc * 64 + j * 16 + l15;
            if (p < Ng) {
                const int ih = ihlo + p / nw, iw = iwlo + p % nw;
                const int oh = 3 * ih + dh, ow = 3 * iw + dw;
#pragma unroll
                for (int r = 0; r < 4; r++) {
                    const int oc = oc0 + r;
                    out[((long)(b * 1024 + oc) * 82 + oh) * 82 + ow] = acc[i][j][r] + db[oc];
                }
            }
        }
    }
}

// ---------------- f32 -> bf16 cast (vectorized) ----------------
__global__ __launch_bounds__(256) void cast_f32_bf16_k(const float* __restrict__ in,
                                                       bf16* __restrict__ out, long n) {
    long i = ((long)blockIdx.x * 256 + threadIdx.x) * 4;
    if (i >= n) return;
    float4 v = *(const float4*)(in + i);
    bf16x4 o;
    o[0] = (bf16)v.x; o[1] = (bf16)v.y; o[2] = (bf16)v.z; o[3] = (bf16)v.w;
    *(bf16x4*)(out + i) = o;
}

// ---------------- bf16 tiled transpose (batched) ----------------
// in: [R, C] -> out: [C, R]
__global__ __launch_bounds__(256) void transpose_bf16_k(const bf16* __restrict__ in,
                                                        bf16* __restrict__ out,
                                                        int R, int C, long sIn, long sOut) {
    __shared__ bf16 tile[64][65];
    in += (long)blockIdx.z * sIn;
    out += (long)blockIdx.z * sOut;
    const int r0 = blockIdx.y * 64, c0 = blockIdx.x * 64;
    const int tx = threadIdx.x & 63, ty = threadIdx.x >> 6;
#pragma unroll
    for (int i = 0; i < 16; i++) {
        int r = ty * 16 + i;
        int gr = r0 + r, gc = c0 + tx;
        tile[r][tx] = (gr < R && gc < C) ? in[(long)gr * C + gc] : (bf16)0.f;
    }
    __syncthreads();
#pragma unroll
    for (int i = 0; i < 16; i++) {
        int c = ty * 16 + i;
        int gc = c0 + c, gr = r0 + tx;
        if (gc < C && gr < R) out[(long)gc * R + gr] = tile[tx][c];
    }
}

// ---------------- adjacency: column sums of s^2 (partials + combine) ----------------
__global__ __launch_bounds__(256) void colsum_part_k(const float* __restrict__ s,
                                                     float* __restrict__ part) {
    int m = blockIdx.x * 256 + threadIdx.x;
    if (m >= N_NODES) return;
    int y = blockIdx.y, b = blockIdx.z;
    const float* sb = s + (long)b * N_NODES * N_NODES;
    float acc = 0.f;
    for (int n = y * 196; n < y * 196 + 196; ++n) {
        float v = sb[(long)n * N_NODES + m];
        acc += v * v;
    }
    part[((long)y * 4 + b) * N_NODES + m] = acc;
}

__global__ __launch_bounds__(256) void colsum_comb_k(const float* __restrict__ part,
                                                     float* __restrict__ inv) {
    int m = blockIdx.x * 256 + threadIdx.x;
    if (m >= N_NODES) return;
    int b = blockIdx.y;
    float a = 0.f;
#pragma unroll
    for (int y = 0; y < 8; y++) a += part[((long)y * 4 + b) * N_NODES + m];
    inv[(long)b * N_NODES + m] = 1.0f / a;
}

// lap[n,m] = 0.5 * s^2[n,m] * inv[m] + 0.5*(n==m)   (d == 1/sqrt(2) exactly)
__global__ __launch_bounds__(256) void lap_build_k(const float* __restrict__ s,
                                                   const float* __restrict__ inv,
                                                   bf16* __restrict__ lap) {
    int m = blockIdx.x * 256 + threadIdx.x;
    if (m >= N_NODES) return;
    int n = blockIdx.y, b = blockIdx.z;
    long off = (long)b * N_NODES * N_NODES + (long)n * N_NODES + m;
    float v = s[off];
    float l = 0.5f * v * v * inv[(long)b * N_NODES + m];
    if (n == m) l += 0.5f;
    lap[off] = (bf16)l;
}

// ---------------- LayerNorm(2048) + LeakyReLU(0.1), row-per-block ----------------
__global__ __launch_bounds__(256) void ln_leaky_k(const float* __restrict__ y,
                                                  const float* __restrict__ g,
                                                  const float* __restrict__ beta,
                                                  bf16* __restrict__ z) {
    const long row = blockIdx.x;
    const float* yr = y + row * CDIM;
    const int t = threadIdx.x;
    float v[8];
    float s = 0.f, ss = 0.f;
#pragma unroll
    for (int i = 0; i < 8; i++) {
        float x = yr[t + 256 * i];
        v[i] = x; s += x; ss += x * x;
    }
#pragma unroll
    for (int o = 32; o > 0; o >>= 1) {
        s += __shfl_down(s, o);
        ss += __shfl_down(ss, o);
    }
    __shared__ float sh[8];
    const int wave = t >> 6;
    if ((t & 63) == 0) { sh[wave] = s; sh[wave + 4] = ss; }
    __syncthreads();
    if (t == 0) {
        float a = 0.f, b2 = 0.f;
#pragma unroll
        for (int w = 0; w < 4; w++) { a += sh[w]; b2 += sh[w + 4]; }
        sh[0] = a; sh[4] = b2;
    }
    __syncthreads();
    const float mean = sh[0] * (1.f / 2048.f);
    const float var = sh[4] * (1.f / 2048.f) - mean * mean;
    const float invs = rsqrtf(var + 1e-5f);
    bf16* zr = z + row * CDIM;
#pragma unroll
    for (int i = 0; i < 8; i++) {
        int c = t + 256 * i;
        float o = (v[i] - mean) * invs * g[c] + beta[c];
        o = o > 0.f ? o : 0.1f * o;
        zr[c] = (bf16)o;
    }
}

// ---------------- head: conv1 over 8 frame channels ----------------
// t[b][hw][c] = sum_f z[b][f*196+hw][c] * cw[f] + cb
__global__ __launch_bounds__(256) void conv1_k(const bf16* __restrict__ z,
                                               const float* __restrict__ cw,
                                               const float* __restrict__ cb,
                                               bf16* __restrict__ tb) {
    const int b = blockIdx.z, hw = blockIdx.y;
    const int c = blockIdx.x * 256 + threadIdx.x;
    float acc = cb[0];
#pragma unroll
    for (int f = 0; f < 8; f++)
        acc += (float)z[((long)b * N_NODES + f * 196 + hw) * CDIM + c] * cw[f];
    tb[((long)b * 196 + hw) * CDIM + c] = (bf16)acc;
}

// ---------------- bilinear x2 upsample, half-pixel, edge clamp ----------------
__global__ __launch_bounds__(256) void upsample_k(const bf16* __restrict__ tb,
                                                  bf16* __restrict__ u) {
    const int b = blockIdx.z, i = blockIdx.y, j = blockIdx.x;
    const float si = 0.5f * i - 0.25f, sj = 0.5f * j - 0.25f;
    const int i0 = (int)floorf(si), j0 = (int)floorf(sj);
    const float wi = si - i0, wj = sj - j0;
    const int i0c = max(i0, 0), i1c = min(i0 + 1, 13);
    const int j0c = max(j0, 0), j1c = min(j0 + 1, 13);
    const bf16* base = tb + (long)b * 196 * CDIM;
    const long r00 = ((long)i0c * 14 + j0c) * CDIM, r01 = ((long)i0c * 14 + j1c) * CDIM;
    const long r10 = ((long)i1c * 14 + j0c) * CDIM, r11 = ((long)i1c * 14 + j1c) * CDIM;
    bf16* ur = u + ((long)(b * 28 + i) * 28 + j) * CDIM;
    const float w00 = (1.f - wi) * (1.f - wj), w01 = (1.f - wi) * wj;
    const float w10 = wi * (1.f - wj), w11 = wi * wj;
    for (int k = 0; k < 8; k++) {
        int cc = threadIdx.x + 256 * k;
        float v = w00 * (float)base[r00 + cc] + w01 * (float)base[r01 + cc] +
                  w10 * (float)base[r10 + cc] + w11 * (float)base[r11 + cc];
        ur[cc] = (bf16)v;
    }
}

// ---------------- deconv weight transform ----------------
// Wt[kh][kw][oc][ic] = deconv_w[ic][oc][2-kh][2-kw], cast to bf16
__global__ __launch_bounds__(256) void wt_k(const float* __restrict__ dw,
                                            bf16* __restrict__ Wt) {
    const int ic = blockIdx.x * 256 + threadIdx.x;  // grid.x = 8 -> 2048
    const int oc = blockIdx.y;                      // 1024
    const float* src = dw + ((long)ic * 1024 + oc) * 9;
#pragma unroll
    for (int r = 0; r < 3; r++)
#pragma unroll
        for (int s = 0; s < 3; s++) {
            int kh = 2 - r, kw = 2 - s;
            Wt[((long)(kh * 3 + kw) * 1024 + oc) * 2048 + ic] = (bf16)src[r * 3 + s];
        }
}

// =====================================================================
extern "C" void kernel_launch(void* const* d_in, const int* in_sizes, int n_in,
                              void* d_out, int out_size, void* d_ws, size_t ws_size,
                              hipStream_t stream) {
    const float* x        = (const float*)d_in[0];
    const float* w_fc1    = (const float*)d_in[1];
    const float* w1       = (const float*)d_in[2];
    const float* g1       = (const float*)d_in[3];
    const float* b1       = (const float*)d_in[4];
    const float* w2       = (const float*)d_in[5];
    const float* g2       = (const float*)d_in[6];
    const float* b2       = (const float*)d_in[7];
    const float* w3       = (const float*)d_in[8];
    const float* g3       = (const float*)d_in[9];
    const float* b3       = (const float*)d_in[10];
    const float* conv1_w  = (const float*)d_in[11];
    const float* conv1_b  = (const float*)d_in[12];
    const float* deconv_w = (const float*)d_in[13];
    const float* deconv_b = (const float*)d_in[14];
    float* out = (float*)d_out;

    // ---- workspace layout (bytes) ----
    char* W = (char*)d_ws;
    bf16* wb   = (bf16*)(W + 0);            // 4 x 2048x2048 bf16 = 33,554,432 B
    bf16* xb   = (bf16*)(W + 33554432);     // 6272x2048 bf16 = 25,690,112 B  (later: z)
    bf16* xbT  = (bf16*)(W + 59244544);     // 4 x 2048x1568 bf16 = 25,690,112 B (later: zT)
    bf16* hb   = (bf16*)(W + 84934656);     // 6272x2048 bf16 = 25,690,112 B  (later: outN)
    bf16* lap  = (bf16*)(W + 110624768);    // 4 x 1568x1568 bf16 = 19,668,992 B
    bf16* outT = (bf16*)(W + 130293760);    // 4 x 2048x1568 bf16 = 25,690,112 B
    bf16* tbuf = (bf16*)(W + 155983872);    // 4 x 196x2048 bf16 = 3,211,264 B
    bf16* ubuf = (bf16*)(W + 159195136);    // 4 x 784x2048 bf16 = 12,845,056 B
    bf16* Wt   = (bf16*)(W + 172040192);    // 9 x 1024x2048 bf16 = 37,748,736 B
    float* ybuf = (float*)(W + 209788928);  // 6272x2048 f32 = 51,380,224 B
    float* sbuf = (float*)(W + 209788928);  // s overlays y (s dead before first y write)
    float* part = (float*)(W + 261169152);  // 8x4x1568 f32
    float* invc = (float*)(W + 261369856);  // 4x1568 f32
    bf16* zb = xb;    // reuse (xb dead after fc1 + transpose)
    bf16* zT = xbT;   // reuse (xbT dead after layer-1 lap GEMM)
    bf16* outN = hb;  // reuse (hb dead after s GEMM)

    const long WMAT = (long)2048 * 2048;
    bf16* wb0 = wb, *wb1 = wb + WMAT, *wb2 = wb + 2 * WMAT, *wb3 = wb + 3 * WMAT;

    // ---- weight / input casts ----
    cast_f32_bf16_k<<<dim3(4096), 256, 0, stream>>>(w_fc1, wb0, WMAT);
    cast_f32_bf16_k<<<dim3(4096), 256, 0, stream>>>(w1, wb1, WMAT);
    cast_f32_bf16_k<<<dim3(4096), 256, 0, stream>>>(w2, wb2, WMAT);
    cast_f32_bf16_k<<<dim3(4096), 256, 0, stream>>>(w3, wb3, WMAT);
    cast_f32_bf16_k<<<dim3(12544), 256, 0, stream>>>(x, xb, (long)6272 * 2048);
    wt_k<<<dim3(8, 1024), 256, 0, stream>>>(deconv_w, Wt);

    // xbT = per-batch transpose of xb: [1568,2048] -> [2048,1568]
    transpose_bf16_k<<<dim3(32, 25, 4), 256, 0, stream>>>(
        xb, xbT, N_NODES, CDIM, (long)N_NODES * CDIM, (long)N_NODES * CDIM);

    // ---- h = x @ w_fc1^T  (NT: M=6272,N=2048,K=2048) ----
    gemm_nt<bf16><<<dim3(49, 16, 1), 256, 0, stream>>>(
        xb, wb0, hb, 6272, 2048, 2048, 0, 0, 0);

    // ---- s = h h^T per batch (NT: M=N=1568, K=2048) ----
    gemm_nt<float><<<dim3(13, 13, 4), 256, 0, stream>>>(
        hb, hb, sbuf, N_NODES, N_NODES, 2048,
        (long)N_NODES * 2048, (long)N_NODES * 2048, (long)N_NODES * N_NODES);

    // ---- lap = 0.5*s^2/colsum + 0.5*I ----
    colsum_part_k<<<dim3(7, 8, 4), 256, 0, stream>>>(sbuf, part);
    colsum_comb_k<<<dim3(7, 4), 256, 0, stream>>>(part, invc);
    lap_build_k<<<dim3(7, N_NODES, 4), 256, 0, stream>>>(sbuf, invc, lap);

    // ---- 3x (lap matmul -> linear -> LN+leaky) ----
    const bf16* wlayer[3] = {wb1, wb2, wb3};
    const float* gl[3] = {g1, g2, g3};
    const float* bl[3] = {b1, b2, b3};
    for (int i = 0; i < 3; i++) {
        const bf16* At = (i == 0) ? xbT : zT;
        // outT = (lap @ prev)^T = NT(prevT, lap): M=2048, N=1568, K=1568, batched
        gemm_nt<bf16><<<dim3(16, 13, 4), 256, 0, stream>>>(
            At, lap, outT, 2048, N_NODES, N_NODES,
            (long)CDIM * N_NODES, (long)N_NODES * N_NODES, (long)CDIM * N_NODES);
        // outN = transpose(outT): [2048,1568] -> [1568,2048]
        transpose_bf16_k<<<dim3(25, 32, 4), 256, 0, stream>>>(
            outT, outN, CDIM, N_NODES, (long)CDIM * N_NODES, (long)CDIM * N_NODES);
        // y = outN @ w^T  (M=6272, N=2048, K=2048)
        gemm_nt<float><<<dim3(49, 16, 1), 256, 0, stream>>>(
            outN, wlayer[i], ybuf, 6272, 2048, 2048, 0, 0, 0);
        // z = leaky(LN(y))
        ln_leaky_k<<<dim3(6272), 256, 0, stream>>>(ybuf, gl[i], bl[i], zb);
        if (i < 2) {
            transpose_bf16_k<<<dim3(32, 25, 4), 256, 0, stream>>>(
                zb, zT, N_NODES, CDIM, (long)N_NODES * CDIM, (long)N_NODES * CDIM);
        }
    }

    // ---- head ----
    conv1_k<<<dim3(8, 196, 4), 256, 0, stream>>>(zb, conv1_w, conv1_b, tbuf);
    upsample_k<<<dim3(28, 28, 4), 256, 0, stream>>>(tbuf, ubuf);
    deconv_gemm<<<dim3(8, 7, 36), 256, 0, stream>>>(Wt, ubuf, deconv_b, out);

    (void)in_sizes; (void)n_in; (void)out_size; (void)ws_size;
}

// Round 2
// 1394.413 us; speedup vs baseline: 1.0002x; 1.0002x over previous
//
#include <hip/hip_runtime.h>

typedef __bf16 bf16;
typedef __bf16 bf16x4 __attribute__((ext_vector_type(4)));
typedef __bf16 bf16x8 __attribute__((ext_vector_type(8)));
typedef float f32x4 __attribute__((ext_vector_type(4)));

#define N_NODES 1568
#define CDIM 2048

// ---------------- async global->LDS 16B ----------------
__device__ __forceinline__ void async_copy16(const bf16* g, bf16* l) {
    __builtin_amdgcn_global_load_lds(
        (const __attribute__((address_space(1))) unsigned int*)g,
        (__attribute__((address_space(3))) unsigned int*)l, 16, 0, 0);
}

// ---------------- generic NT bf16 MFMA GEMM ----------------
// C[M,N] = A[M,K] * B[N,K]^T ; lda=ldb=K, ldc=N. Batched via grid.z with strides.
template <typename OUT_T>
__global__ __launch_bounds__(256) void gemm_nt(const bf16* __restrict__ A,
                                               const bf16* __restrict__ B,
                                               OUT_T* __restrict__ C,
                                               int M, int N, int K,
                                               long sAb, long sBb, long sCb) {
    __shared__ __align__(16) bf16 sA[128 * 32];
    __shared__ __align__(16) bf16 sB[128 * 32];
    const int bz = blockIdx.z;
    A += (long)bz * sAb; B += (long)bz * sBb; C += (long)bz * sCb;
    const int m0 = blockIdx.x * 128, n0 = blockIdx.y * 128;
    const int t = threadIdx.x;
    const int lane = t & 63, wave = t >> 6;
    const int wr = wave >> 1, wc = wave & 1;
    const int l15 = lane & 15, quad = lane >> 4;

    f32x4 acc[4][4];
#pragma unroll
    for (int i = 0; i < 4; i++)
#pragma unroll
        for (int j = 0; j < 4; j++) acc[i][j] = (f32x4){0.f, 0.f, 0.f, 0.f};

    // staging chunks: chunk c (0..511) covers LDS bytes [c*16, c*16+16),
    // global row = c>>2, col elems = (c&3)*8. Thread t handles c=t and c=t+256.
    const int ko = (t & 3) * 8;
    int ra1 = m0 + (t >> 2);          if (ra1 >= M) ra1 = M - 1;
    int ra2 = m0 + ((t + 256) >> 2);  if (ra2 >= M) ra2 = M - 1;
    int rb1 = n0 + (t >> 2);          if (rb1 >= N) rb1 = N - 1;
    int rb2 = n0 + ((t + 256) >> 2);  if (rb2 >= N) rb2 = N - 1;
    const bf16* gA1 = A + (long)ra1 * K + ko;
    const bf16* gA2 = A + (long)ra2 * K + ko;
    const bf16* gB1 = B + (long)rb1 * K + ko;
    const bf16* gB2 = B + (long)rb2 * K + ko;
    bf16* lA1 = sA + t * 8;  bf16* lA2 = sA + (t + 256) * 8;
    bf16* lB1 = sB + t * 8;  bf16* lB2 = sB + (t + 256) * 8;

    for (int k0 = 0; k0 < K; k0 += 32) {
        __syncthreads();
        async_copy16(gA1 + k0, lA1);
        async_copy16(gA2 + k0, lA2);
        async_copy16(gB1 + k0, lB1);
        async_copy16(gB2 + k0, lB2);
        __syncthreads();
        bf16x8 af[4], bfr[4];
#pragma unroll
        for (int i = 0; i < 4; i++)
            af[i] = *(const bf16x8*)(sA + (wr * 64 + i * 16 + l15) * 32 + quad * 8);
#pragma unroll
        for (int j = 0; j < 4; j++)
            bfr[j] = *(const bf16x8*)(sB + (wc * 64 + j * 16 + l15) * 32 + quad * 8);
#pragma unroll
        for (int i = 0; i < 4; i++)
#pragma unroll
            for (int j = 0; j < 4; j++)
                acc[i][j] = __builtin_amdgcn_mfma_f32_16x16x32_bf16(af[i], bfr[j], acc[i][j], 0, 0, 0);
    }
    // epilogue: D[row=quad*4+r][col=l15] per 16x16 tile (m89-verified layout)
#pragma unroll
    for (int i = 0; i < 4; i++) {
        const int row0 = m0 + wr * 64 + i * 16 + quad * 4;
#pragma unroll
        for (int j = 0; j < 4; j++) {
            const int col = n0 + wc * 64 + j * 16 + l15;
            if (col < N) {
#pragma unroll
                for (int r = 0; r < 4; r++) {
                    const int row = row0 + r;
                    if (row < M) C[(long)row * N + col] = (OUT_T)acc[i][j][r];
                }
            }
        }
    }
}

// ---------------- f32 -> bf16 cast (vectorized) ----------------
__global__ __launch_bounds__(256) void cast_f32_bf16_k(const float* __restrict__ in,
                                                       bf16* __restrict__ out, long n) {
    long i = ((long)blockIdx.x * 256 + threadIdx.x) * 4;
    if (i >= n) return;
    float4 v = *(const float4*)(in + i);
    bf16x4 o;
    o[0] = (bf16)v.x; o[1] = (bf16)v.y; o[2] = (bf16)v.z; o[3] = (bf16)v.w;
    *(bf16x4*)(out + i) = o;
}

// 4 equal-size weight matrices in one launch (blockIdx.y selects)
__global__ __launch_bounds__(256) void cast4_f32_bf16_k(const float* __restrict__ a,
                                                        const float* __restrict__ b,
                                                        const float* __restrict__ c,
                                                        const float* __restrict__ d,
                                                        bf16* __restrict__ out, long n) {
    const int w = blockIdx.y;
    const float* in = (w == 0) ? a : (w == 1) ? b : (w == 2) ? c : d;
    bf16* o = out + (long)w * n;
    long i = ((long)blockIdx.x * 256 + threadIdx.x) * 4;
    if (i >= n) return;
    float4 v = *(const float4*)(in + i);
    bf16x4 ov;
    ov[0] = (bf16)v.x; ov[1] = (bf16)v.y; ov[2] = (bf16)v.z; ov[3] = (bf16)v.w;
    *(bf16x4*)(o + i) = ov;
}

// ---------------- bf16 tiled transpose (batched) ----------------
// in: [R, C] -> out: [C, R]
__global__ __launch_bounds__(256) void transpose_bf16_k(const bf16* __restrict__ in,
                                                        bf16* __restrict__ out,
                                                        int R, int C, long sIn, long sOut) {
    __shared__ bf16 tile[64][65];
    in += (long)blockIdx.z * sIn;
    out += (long)blockIdx.z * sOut;
    const int r0 = blockIdx.y * 64, c0 = blockIdx.x * 64;
    const int tx = threadIdx.x & 63, ty = threadIdx.x >> 6;
#pragma unroll
    for (int i = 0; i < 16; i++) {
        int r = ty * 16 + i;
        int gr = r0 + r, gc = c0 + tx;
        tile[r][tx] = (gr < R && gc < C) ? in[(long)gr * C + gc] : (bf16)0.f;
    }
    __syncthreads();
#pragma unroll
    for (int i = 0; i < 16; i++) {
        int c = ty * 16 + i;
        int gc = c0 + c, gr = r0 + tx;
        if (gc < C && gr < R) out[(long)gc * R + gr] = tile[tx][c];
    }
}

// ---------------- adjacency: column sums of s^2 (partials + combine) ----------------
__global__ __launch_bounds__(256) void colsum_part_k(const float* __restrict__ s,
                                                     float* __restrict__ part) {
    int m = blockIdx.x * 256 + threadIdx.x;
    if (m >= N_NODES) return;
    int y = blockIdx.y, b = blockIdx.z;
    const float* sb = s + (long)b * N_NODES * N_NODES;
    float acc = 0.f;
    for (int n = y * 196; n < y * 196 + 196; ++n) {
        float v = sb[(long)n * N_NODES + m];
        acc += v * v;
    }
    part[((long)y * 4 + b) * N_NODES + m] = acc;
}

__global__ __launch_bounds__(256) void colsum_comb_k(const float* __restrict__ part,
                                                     float* __restrict__ inv) {
    int m = blockIdx.x * 256 + threadIdx.x;
    if (m >= N_NODES) return;
    int b = blockIdx.y;
    float a = 0.f;
#pragma unroll
    for (int y = 0; y < 8; y++) a += part[((long)y * 4 + b) * N_NODES + m];
    inv[(long)b * N_NODES + m] = 1.0f / a;
}

// lap[n,m] = 0.5 * s^2[n,m] * inv[m] + 0.5*(n==m)   (d == 1/sqrt(2) exactly)
__global__ __launch_bounds__(256) void lap_build_k(const float* __restrict__ s,
                                                   const float* __restrict__ inv,
                                                   bf16* __restrict__ lap) {
    int m = blockIdx.x * 256 + threadIdx.x;
    if (m >= N_NODES) return;
    int n = blockIdx.y, b = blockIdx.z;
    long off = (long)b * N_NODES * N_NODES + (long)n * N_NODES + m;
    float v = s[off];
    float l = 0.5f * v * v * inv[(long)b * N_NODES + m];
    if (n == m) l += 0.5f;
    lap[off] = (bf16)l;
}

// ---------------- LayerNorm(2048) + LeakyReLU(0.1), row-per-block ----------------
__global__ __launch_bounds__(256) void ln_leaky_k(const float* __restrict__ y,
                                                  const float* __restrict__ g,
                                                  const float* __restrict__ beta,
                                                  bf16* __restrict__ z) {
    const long row = blockIdx.x;
    const float* yr = y + row * CDIM;
    const int t = threadIdx.x;
    float v[8];
    float s = 0.f, ss = 0.f;
#pragma unroll
    for (int i = 0; i < 8; i++) {
        float x = yr[t + 256 * i];
        v[i] = x; s += x; ss += x * x;
    }
#pragma unroll
    for (int o = 32; o > 0; o >>= 1) {
        s += __shfl_down(s, o);
        ss += __shfl_down(ss, o);
    }
    __shared__ float sh[8];
    const int wave = t >> 6;
    if ((t & 63) == 0) { sh[wave] = s; sh[wave + 4] = ss; }
    __syncthreads();
    if (t == 0) {
        float a = 0.f, b2 = 0.f;
#pragma unroll
        for (int w = 0; w < 4; w++) { a += sh[w]; b2 += sh[w + 4]; }
        sh[0] = a; sh[4] = b2;
    }
    __syncthreads();
    const float mean = sh[0] * (1.f / 2048.f);
    const float var = sh[4] * (1.f / 2048.f) - mean * mean;
    const float invs = rsqrtf(var + 1e-5f);
    bf16* zr = z + row * CDIM;
#pragma unroll
    for (int i = 0; i < 8; i++) {
        int c = t + 256 * i;
        float o = (v[i] - mean) * invs * g[c] + beta[c];
        o = o > 0.f ? o : 0.1f * o;
        zr[c] = (bf16)o;
    }
}

// ---------------- head: conv1 over 8 frame channels ----------------
// t[b][hw][c] = sum_f z[b][f*196+hw][c] * cw[f] + cb
__global__ __launch_bounds__(256) void conv1_k(const bf16* __restrict__ z,
                                               const float* __restrict__ cw,
                                               const float* __restrict__ cb,
                                               bf16* __restrict__ tb) {
    const int b = blockIdx.z, hw = blockIdx.y;
    const int c = blockIdx.x * 256 + threadIdx.x;
    float acc = cb[0];
#pragma unroll
    for (int f = 0; f < 8; f++)
        acc += (float)z[((long)b * N_NODES + f * 196 + hw) * CDIM + c] * cw[f];
    tb[((long)b * 196 + hw) * CDIM + c] = (bf16)acc;
}

// ---------------- bilinear x2 upsample, half-pixel, edge clamp ----------------
__global__ __launch_bounds__(256) void upsample_k(const bf16* __restrict__ tb,
                                                  bf16* __restrict__ u) {
    const int b = blockIdx.z, i = blockIdx.y, j = blockIdx.x;
    const float si = 0.5f * i - 0.25f, sj = 0.5f * j - 0.25f;
    const int i0 = (int)floorf(si), j0 = (int)floorf(sj);
    const float wi = si - i0, wj = sj - j0;
    const int i0c = max(i0, 0), i1c = min(i0 + 1, 13);
    const int j0c = max(j0, 0), j1c = min(j0 + 1, 13);
    const bf16* base = tb + (long)b * 196 * CDIM;
    const long r00 = ((long)i0c * 14 + j0c) * CDIM, r01 = ((long)i0c * 14 + j1c) * CDIM;
    const long r10 = ((long)i1c * 14 + j0c) * CDIM, r11 = ((long)i1c * 14 + j1c) * CDIM;
    bf16* ur = u + ((long)(b * 28 + i) * 28 + j) * CDIM;
    const float w00 = (1.f - wi) * (1.f - wj), w01 = (1.f - wi) * wj;
    const float w10 = wi * (1.f - wj), w11 = wi * wj;
    for (int k = 0; k < 8; k++) {
        int cc = threadIdx.x + 256 * k;
        float v = w00 * (float)base[r00 + cc] + w01 * (float)base[r01 + cc] +
                  w10 * (float)base[r10 + cc] + w11 * (float)base[r11 + cc];
        ur[cc] = (bf16)v;
    }
}

// ---------------- deconv weight transform ----------------
// Wt[kh][kw][oc][ic] = deconv_w[ic][oc][2-kh][2-kw], cast to bf16
__global__ __launch_bounds__(256) void wt_k(const float* __restrict__ dw,
                                            bf16* __restrict__ Wt) {
    const int ic = blockIdx.x * 256 + threadIdx.x;  // grid.x = 8 -> 2048
    const int oc = blockIdx.y;                      // 1024
    const float* src = dw + ((long)ic * 1024 + oc) * 9;
#pragma unroll
    for (int r = 0; r < 3; r++)
#pragma unroll
        for (int s = 0; s < 3; s++) {
            int kh = 2 - r, kw = 2 - s;
            Wt[((long)(kh * 3 + kw) * 1024 + oc) * 2048 + ic] = (bf16)src[r * 3 + s];
        }
}

// ---------------- deconv scatter: r[g*1024+oc][b*784+p] -> out[b][oc][82][82] ----------------
__global__ __launch_bounds__(256) void deconv_scatter_k(const float* __restrict__ r,
                                                        const float* __restrict__ db,
                                                        float* __restrict__ out) {
    const int blk = blockIdx.x;          // 4096 = b*1024 + oc
    const int b = blk >> 10, oc = blk & 1023;
    const float bias = db[oc];
    float* ob = out + (long)blk * 82 * 82;
    for (int e = threadIdx.x; e < 82 * 82; e += 256) {
        const int oh = e / 82, ow = e - oh * 82;
        const int mh = oh % 3, mw = ow % 3;
        const int kh = (mh == 0) ? 1 : ((mh == 1) ? 0 : 2);
        const int kw = (mw == 0) ? 1 : ((mw == 1) ? 0 : 2);
        const int ih = (oh - (1 - kh)) / 3;
        const int iw = (ow - (1 - kw)) / 3;
        const int g = kh * 3 + kw;
        ob[e] = r[(long)(g * 1024 + oc) * 3136 + b * 784 + ih * 28 + iw] + bias;
    }
}

// =====================================================================
extern "C" void kernel_launch(void* const* d_in, const int* in_sizes, int n_in,
                              void* d_out, int out_size, void* d_ws, size_t ws_size,
                              hipStream_t stream) {
    const float* x        = (const float*)d_in[0];
    const float* w_fc1    = (const float*)d_in[1];
    const float* w1       = (const float*)d_in[2];
    const float* g1       = (const float*)d_in[3];
    const float* b1       = (const float*)d_in[4];
    const float* w2       = (const float*)d_in[5];
    const float* g2       = (const float*)d_in[6];
    const float* b2       = (const float*)d_in[7];
    const float* w3       = (const float*)d_in[8];
    const float* g3       = (const float*)d_in[9];
    const float* b3       = (const float*)d_in[10];
    const float* conv1_w  = (const float*)d_in[11];
    const float* conv1_b  = (const float*)d_in[12];
    const float* deconv_w = (const float*)d_in[13];
    const float* deconv_b = (const float*)d_in[14];
    float* out = (float*)d_out;

    // ---- workspace layout (bytes) ----
    char* W = (char*)d_ws;
    bf16* wb   = (bf16*)(W + 0);            // 4 x 2048x2048 bf16 = 33,554,432
    bf16* xb   = (bf16*)(W + 33554432);     // 6272x2048 bf16 (later: z)
    bf16* xbT  = (bf16*)(W + 59244544);     // 4 x 2048x1568 bf16 (later: zT)
    bf16* hb   = (bf16*)(W + 84934656);     // 6272x2048 bf16 (later: outN)
    bf16* lap  = (bf16*)(W + 110624768);    // 4 x 1568x1568 bf16 = 19,668,992
    bf16* tbuf = (bf16*)(W + 130293760);    // 4 x 196x2048 bf16 = 3,211,264
    bf16* ubuf = (bf16*)(W + 133505024);    // 4 x 784x2048 bf16 = 12,845,056
    bf16* Wt   = (bf16*)(W + 146350080);    // 9 x 1024x2048 bf16 = 37,748,736
    float* ybuf = (float*)(W + 184098816);  // 6272x2048 f32 = 51,380,224
    float* sbuf = (float*)(W + 184098816);  // s overlays y (dead before first y write)
    float* part = (float*)(W + 235479040);  // 8x4x1568 f32
    float* invc = (float*)(W + 235679744);  // 4x1568 f32
    // rbuf overlays wb/xb/xbT/hb/lap-head: all dead by the time deconv GEMM runs
    float* rbuf = (float*)(W + 0);          // 9216 x 3136 f32 = 115,605,504
    bf16* zb = xb;    // reuse (xb dead after fc1 + transpose)
    bf16* zT = xbT;   // reuse (xbT dead after layer-0 lap GEMM)
    bf16* outN = hb;  // reuse (hb dead after s GEMM)

    const long WMAT = (long)2048 * 2048;
    bf16* wb0 = wb, *wb1 = wb + WMAT, *wb2 = wb + 2 * WMAT, *wb3 = wb + 3 * WMAT;

    // ---- weight / input casts ----
    cast4_f32_bf16_k<<<dim3(4096, 4), 256, 0, stream>>>(w_fc1, w1, w2, w3, wb, WMAT);
    cast_f32_bf16_k<<<dim3(12544), 256, 0, stream>>>(x, xb, (long)6272 * 2048);
    wt_k<<<dim3(8, 1024), 256, 0, stream>>>(deconv_w, Wt);

    // xbT = per-batch transpose of xb: [1568,2048] -> [2048,1568]
    transpose_bf16_k<<<dim3(32, 25, 4), 256, 0, stream>>>(
        xb, xbT, N_NODES, CDIM, (long)N_NODES * CDIM, (long)N_NODES * CDIM);

    // ---- h = x @ w_fc1^T  (NT: M=6272,N=2048,K=2048) ----
    gemm_nt<bf16><<<dim3(49, 16, 1), 256, 0, stream>>>(
        xb, wb0, hb, 6272, 2048, 2048, 0, 0, 0);

    // ---- s = h h^T per batch (NT: M=N=1568, K=2048) ----
    gemm_nt<float><<<dim3(13, 13, 4), 256, 0, stream>>>(
        hb, hb, sbuf, N_NODES, N_NODES, 2048,
        (long)N_NODES * 2048, (long)N_NODES * 2048, (long)N_NODES * N_NODES);

    // ---- lap = 0.5*s^2/colsum + 0.5*I ----
    colsum_part_k<<<dim3(7, 8, 4), 256, 0, stream>>>(sbuf, part);
    colsum_comb_k<<<dim3(7, 4), 256, 0, stream>>>(part, invc);
    lap_build_k<<<dim3(7, N_NODES, 4), 256, 0, stream>>>(sbuf, invc, lap);

    // ---- 3x (lap matmul -> linear -> LN+leaky) ----
    const bf16* wlayer[3] = {wb1, wb2, wb3};
    const float* gl[3] = {g1, g2, g3};
    const float* bl[3] = {b1, b2, b3};
    for (int i = 0; i < 3; i++) {
        const bf16* prevT = (i == 0) ? xbT : zT;
        // outN = lap @ prev = NT(lap, prevT): M=1568, N=2048, K=1568, batched
        gemm_nt<bf16><<<dim3(13, 16, 4), 256, 0, stream>>>(
            lap, prevT, outN, N_NODES, CDIM, N_NODES,
            (long)N_NODES * N_NODES, (long)CDIM * N_NODES, (long)N_NODES * CDIM);
        // y = outN @ w^T  (M=6272, N=2048, K=2048)
        gemm_nt<float><<<dim3(49, 16, 1), 256, 0, stream>>>(
            outN, wlayer[i], ybuf, 6272, 2048, 2048, 0, 0, 0);
        // z = leaky(LN(y))
        ln_leaky_k<<<dim3(6272), 256, 0, stream>>>(ybuf, gl[i], bl[i], zb);
        if (i < 2) {
            transpose_bf16_k<<<dim3(32, 25, 4), 256, 0, stream>>>(
                zb, zT, N_NODES, CDIM, (long)N_NODES * CDIM, (long)N_NODES * CDIM);
        }
    }

    // ---- head ----
    conv1_k<<<dim3(8, 196, 4), 256, 0, stream>>>(zb, conv1_w, conv1_b, tbuf);
    upsample_k<<<dim3(28, 28, 4), 256, 0, stream>>>(tbuf, ubuf);
    // deconv as single GEMM: C[g*1024+oc][b*784+pix] = Wt[9216,2048] x u[3136,2048]^T
    gemm_nt<float><<<dim3(72, 25, 1), 256, 0, stream>>>(
        Wt, ubuf, rbuf, 9216, 3136, 2048, 0, 0, 0);
    deconv_scatter_k<<<dim3(4096), 256, 0, stream>>>(rbuf, deconv_b, out);

    (void)in_sizes; (void)n_in; (void)out_size; (void)ws_size;
}

// Round 3
// 1261.654 us; speedup vs baseline: 1.1055x; 1.1052x over previous
//
#include <hip/hip_runtime.h>

typedef __bf16 bf16;
typedef __bf16 bf16x4 __attribute__((ext_vector_type(4)));
typedef __bf16 bf16x8 __attribute__((ext_vector_type(8)));
typedef float f32x4 __attribute__((ext_vector_type(4)));

#define N_NODES 1568
#define CDIM 2048

// ---------------- async global->LDS 16B ----------------
__device__ __forceinline__ void async_copy16(const bf16* g, bf16* l) {
    __builtin_amdgcn_global_load_lds(
        (const __attribute__((address_space(1))) unsigned int*)g,
        (__attribute__((address_space(3))) unsigned int*)l, 16, 0, 0);
}

// ---------------- generic NT bf16 MFMA GEMM ----------------
// C[M,N] = A[M,K] * B[N,K]^T ; lda=ldb=K, ldc=N. Batched via grid.z with strides.
// launch_bounds(256,2): cap 256 VGPR so the allocator can hoist addresses
// (bare (256) squeezed to 64 VGPR -> VALU-bound address recompute, R2 evidence)
template <typename OUT_T>
__global__ __launch_bounds__(256, 2) void gemm_nt(const bf16* __restrict__ A,
                                                  const bf16* __restrict__ B,
                                                  OUT_T* __restrict__ C,
                                                  int M, int N, int K,
                                                  long sAb, long sBb, long sCb) {
    __shared__ __align__(16) bf16 sA[128 * 32];
    __shared__ __align__(16) bf16 sB[128 * 32];
    const int bz = blockIdx.z;
    A += (long)bz * sAb; B += (long)bz * sBb; C += (long)bz * sCb;
    const int m0 = blockIdx.x * 128, n0 = blockIdx.y * 128;
    const int t = threadIdx.x;
    const int lane = t & 63, wave = t >> 6;
    const int wr = wave >> 1, wc = wave & 1;
    const int l15 = lane & 15, quad = lane >> 4;

    f32x4 acc[4][4];
#pragma unroll
    for (int i = 0; i < 4; i++)
#pragma unroll
        for (int j = 0; j < 4; j++) acc[i][j] = (f32x4){0.f, 0.f, 0.f, 0.f};

    const int ko = (t & 3) * 8;
    int ra1 = m0 + (t >> 2);          if (ra1 >= M) ra1 = M - 1;
    int ra2 = m0 + ((t + 256) >> 2);  if (ra2 >= M) ra2 = M - 1;
    int rb1 = n0 + (t >> 2);          if (rb1 >= N) rb1 = N - 1;
    int rb2 = n0 + ((t + 256) >> 2);  if (rb2 >= N) rb2 = N - 1;
    const bf16* gA1 = A + (long)ra1 * K + ko;
    const bf16* gA2 = A + (long)ra2 * K + ko;
    const bf16* gB1 = B + (long)rb1 * K + ko;
    const bf16* gB2 = B + (long)rb2 * K + ko;
    bf16* lA1 = sA + t * 8;  bf16* lA2 = sA + (t + 256) * 8;
    bf16* lB1 = sB + t * 8;  bf16* lB2 = sB + (t + 256) * 8;

    for (int k0 = 0; k0 < K; k0 += 32) {
        __syncthreads();
        async_copy16(gA1 + k0, lA1);
        async_copy16(gA2 + k0, lA2);
        async_copy16(gB1 + k0, lB1);
        async_copy16(gB2 + k0, lB2);
        __syncthreads();
        bf16x8 af[4], bfr[4];
#pragma unroll
        for (int i = 0; i < 4; i++)
            af[i] = *(const bf16x8*)(sA + (wr * 64 + i * 16 + l15) * 32 + quad * 8);
#pragma unroll
        for (int j = 0; j < 4; j++)
            bfr[j] = *(const bf16x8*)(sB + (wc * 64 + j * 16 + l15) * 32 + quad * 8);
#pragma unroll
        for (int i = 0; i < 4; i++)
#pragma unroll
            for (int j = 0; j < 4; j++)
                acc[i][j] = __builtin_amdgcn_mfma_f32_16x16x32_bf16(af[i], bfr[j], acc[i][j], 0, 0, 0);
    }
    // epilogue: D[row=quad*4+r][col=l15] per 16x16 tile (m89-verified layout)
#pragma unroll
    for (int i = 0; i < 4; i++) {
        const int row0 = m0 + wr * 64 + i * 16 + quad * 4;
#pragma unroll
        for (int j = 0; j < 4; j++) {
            const int col = n0 + wc * 64 + j * 16 + l15;
            if (col < N) {
#pragma unroll
                for (int r = 0; r < 4; r++) {
                    const int row = row0 + r;
                    if (row < M) C[(long)row * N + col] = (OUT_T)acc[i][j][r];
                }
            }
        }
    }
}

// ---------------- symmetric NT GEMM: C = A A^T (f32 out) ----------------
// Only upper-triangle tiles computed (linear grid.x over 91 tiles), mirrored
// into the lower triangle in the epilogue. M == N.
__global__ __launch_bounds__(256, 2) void gemm_nt_sym(const bf16* __restrict__ A,
                                                      float* __restrict__ C,
                                                      int M, int K,
                                                      long sAb, long sCb) {
    __shared__ __align__(16) bf16 sA[128 * 32];
    __shared__ __align__(16) bf16 sB[128 * 32];
    const int bz = blockIdx.z;
    A += (long)bz * sAb; C += (long)bz * sCb;
    // decode triangular tile id -> (bi, bj), bj >= bi, 13 tiles per side
    int rem = blockIdx.x, bi = 0;
    while (rem >= 13 - bi) { rem -= 13 - bi; bi++; }
    const int bj = bi + rem;
    const int m0 = bi * 128, n0 = bj * 128;
    const int t = threadIdx.x;
    const int lane = t & 63, wave = t >> 6;
    const int wr = wave >> 1, wc = wave & 1;
    const int l15 = lane & 15, quad = lane >> 4;

    f32x4 acc[4][4];
#pragma unroll
    for (int i = 0; i < 4; i++)
#pragma unroll
        for (int j = 0; j < 4; j++) acc[i][j] = (f32x4){0.f, 0.f, 0.f, 0.f};

    const int ko = (t & 3) * 8;
    int ra1 = m0 + (t >> 2);          if (ra1 >= M) ra1 = M - 1;
    int ra2 = m0 + ((t + 256) >> 2);  if (ra2 >= M) ra2 = M - 1;
    int rb1 = n0 + (t >> 2);          if (rb1 >= M) rb1 = M - 1;
    int rb2 = n0 + ((t + 256) >> 2);  if (rb2 >= M) rb2 = M - 1;
    const bf16* gA1 = A + (long)ra1 * K + ko;
    const bf16* gA2 = A + (long)ra2 * K + ko;
    const bf16* gB1 = A + (long)rb1 * K + ko;
    const bf16* gB2 = A + (long)rb2 * K + ko;
    bf16* lA1 = sA + t * 8;  bf16* lA2 = sA + (t + 256) * 8;
    bf16* lB1 = sB + t * 8;  bf16* lB2 = sB + (t + 256) * 8;

    for (int k0 = 0; k0 < K; k0 += 32) {
        __syncthreads();
        async_copy16(gA1 + k0, lA1);
        async_copy16(gA2 + k0, lA2);
        async_copy16(gB1 + k0, lB1);
        async_copy16(gB2 + k0, lB2);
        __syncthreads();
        bf16x8 af[4], bfr[4];
#pragma unroll
        for (int i = 0; i < 4; i++)
            af[i] = *(const bf16x8*)(sA + (wr * 64 + i * 16 + l15) * 32 + quad * 8);
#pragma unroll
        for (int j = 0; j < 4; j++)
            bfr[j] = *(const bf16x8*)(sB + (wc * 64 + j * 16 + l15) * 32 + quad * 8);
#pragma unroll
        for (int i = 0; i < 4; i++)
#pragma unroll
            for (int j = 0; j < 4; j++)
                acc[i][j] = __builtin_amdgcn_mfma_f32_16x16x32_bf16(af[i], bfr[j], acc[i][j], 0, 0, 0);
    }
    const bool mirror = (bi != bj);
#pragma unroll
    for (int i = 0; i < 4; i++) {
        const int row0 = m0 + wr * 64 + i * 16 + quad * 4;
#pragma unroll
        for (int j = 0; j < 4; j++) {
            const int col = n0 + wc * 64 + j * 16 + l15;
            if (col < M) {
#pragma unroll
                for (int r = 0; r < 4; r++) {
                    const int row = row0 + r;
                    if (row < M) {
                        const float v = acc[i][j][r];
                        C[(long)row * M + col] = v;
                        if (mirror) C[(long)col * M + row] = v;
                    }
                }
            }
        }
    }
}

// ---------------- f32 -> bf16 cast (vectorized) ----------------
__global__ __launch_bounds__(256) void cast_f32_bf16_k(const float* __restrict__ in,
                                                       bf16* __restrict__ out, long n) {
    long i = ((long)blockIdx.x * 256 + threadIdx.x) * 4;
    if (i >= n) return;
    float4 v = *(const float4*)(in + i);
    bf16x4 o;
    o[0] = (bf16)v.x; o[1] = (bf16)v.y; o[2] = (bf16)v.z; o[3] = (bf16)v.w;
    *(bf16x4*)(out + i) = o;
}

// 4 equal-size weight matrices in one launch (blockIdx.y selects)
__global__ __launch_bounds__(256) void cast4_f32_bf16_k(const float* __restrict__ a,
                                                        const float* __restrict__ b,
                                                        const float* __restrict__ c,
                                                        const float* __restrict__ d,
                                                        bf16* __restrict__ out, long n) {
    const int w = blockIdx.y;
    const float* in = (w == 0) ? a : (w == 1) ? b : (w == 2) ? c : d;
    bf16* o = out + (long)w * n;
    long i = ((long)blockIdx.x * 256 + threadIdx.x) * 4;
    if (i >= n) return;
    float4 v = *(const float4*)(in + i);
    bf16x4 ov;
    ov[0] = (bf16)v.x; ov[1] = (bf16)v.y; ov[2] = (bf16)v.z; ov[3] = (bf16)v.w;
    *(bf16x4*)(o + i) = ov;
}

// ---------------- bf16 tiled transpose (batched) ----------------
__global__ __launch_bounds__(256) void transpose_bf16_k(const bf16* __restrict__ in,
                                                        bf16* __restrict__ out,
                                                        int R, int C, long sIn, long sOut) {
    __shared__ bf16 tile[64][65];
    in += (long)blockIdx.z * sIn;
    out += (long)blockIdx.z * sOut;
    const int r0 = blockIdx.y * 64, c0 = blockIdx.x * 64;
    const int tx = threadIdx.x & 63, ty = threadIdx.x >> 6;
#pragma unroll
    for (int i = 0; i < 16; i++) {
        int r = ty * 16 + i;
        int gr = r0 + r, gc = c0 + tx;
        tile[r][tx] = (gr < R && gc < C) ? in[(long)gr * C + gc] : (bf16)0.f;
    }
    __syncthreads();
#pragma unroll
    for (int i = 0; i < 16; i++) {
        int c = ty * 16 + i;
        int gc = c0 + c, gr = r0 + tx;
        if (gc < C && gr < R) out[(long)gc * R + gr] = tile[tx][c];
    }
}

// ---------------- adjacency: column sums of s^2 (partials + combine) ----------------
__global__ __launch_bounds__(256) void colsum_part_k(const float* __restrict__ s,
                                                     float* __restrict__ part) {
    int m = blockIdx.x * 256 + threadIdx.x;
    if (m >= N_NODES) return;
    int y = blockIdx.y, b = blockIdx.z;
    const float* sb = s + (long)b * N_NODES * N_NODES;
    float acc = 0.f;
    for (int n = y * 196; n < y * 196 + 196; ++n) {
        float v = sb[(long)n * N_NODES + m];
        acc += v * v;
    }
    part[((long)y * 4 + b) * N_NODES + m] = acc;
}

__global__ __launch_bounds__(256) void colsum_comb_k(const float* __restrict__ part,
                                                     float* __restrict__ inv) {
    int m = blockIdx.x * 256 + threadIdx.x;
    if (m >= N_NODES) return;
    int b = blockIdx.y;
    float a = 0.f;
#pragma unroll
    for (int y = 0; y < 8; y++) a += part[((long)y * 4 + b) * N_NODES + m];
    inv[(long)b * N_NODES + m] = 1.0f / a;
}

// lap[n,m] = 0.5 * s^2[n,m] * inv[m] + 0.5*(n==m)   (d == 1/sqrt(2) exactly)
__global__ __launch_bounds__(256) void lap_build_k(const float* __restrict__ s,
                                                   const float* __restrict__ inv,
                                                   bf16* __restrict__ lap) {
    int m = blockIdx.x * 256 + threadIdx.x;
    if (m >= N_NODES) return;
    int n = blockIdx.y, b = blockIdx.z;
    long off = (long)b * N_NODES * N_NODES + (long)n * N_NODES + m;
    float v = s[off];
    float l = 0.5f * v * v * inv[(long)b * N_NODES + m];
    if (n == m) l += 0.5f;
    lap[off] = (bf16)l;
}

// ---------------- LayerNorm(2048) + LeakyReLU(0.1), row-per-block ----------------
__global__ __launch_bounds__(256) void ln_leaky_k(const float* __restrict__ y,
                                                  const float* __restrict__ g,
                                                  const float* __restrict__ beta,
                                                  bf16* __restrict__ z) {
    const long row = blockIdx.x;
    const float* yr = y + row * CDIM;
    const int t = threadIdx.x;
    float v[8];
    float s = 0.f, ss = 0.f;
#pragma unroll
    for (int i = 0; i < 8; i++) {
        float x = yr[t + 256 * i];
        v[i] = x; s += x; ss += x * x;
    }
#pragma unroll
    for (int o = 32; o > 0; o >>= 1) {
        s += __shfl_down(s, o);
        ss += __shfl_down(ss, o);
    }
    __shared__ float sh[8];
    const int wave = t >> 6;
    if ((t & 63) == 0) { sh[wave] = s; sh[wave + 4] = ss; }
    __syncthreads();
    if (t == 0) {
        float a = 0.f, b2 = 0.f;
#pragma unroll
        for (int w = 0; w < 4; w++) { a += sh[w]; b2 += sh[w + 4]; }
        sh[0] = a; sh[4] = b2;
    }
    __syncthreads();
    const float mean = sh[0] * (1.f / 2048.f);
    const float var = sh[4] * (1.f / 2048.f) - mean * mean;
    const float invs = rsqrtf(var + 1e-5f);
    bf16* zr = z + row * CDIM;
#pragma unroll
    for (int i = 0; i < 8; i++) {
        int c = t + 256 * i;
        float o = (v[i] - mean) * invs * g[c] + beta[c];
        o = o > 0.f ? o : 0.1f * o;
        zr[c] = (bf16)o;
    }
}

// ---------------- head: conv1 over 8 frame channels ----------------
__global__ __launch_bounds__(256) void conv1_k(const bf16* __restrict__ z,
                                               const float* __restrict__ cw,
                                               const float* __restrict__ cb,
                                               bf16* __restrict__ tb) {
    const int b = blockIdx.z, hw = blockIdx.y;
    const int c = blockIdx.x * 256 + threadIdx.x;
    float acc = cb[0];
#pragma unroll
    for (int f = 0; f < 8; f++)
        acc += (float)z[((long)b * N_NODES + f * 196 + hw) * CDIM + c] * cw[f];
    tb[((long)b * 196 + hw) * CDIM + c] = (bf16)acc;
}

// ---------------- bilinear x2 upsample, half-pixel, edge clamp ----------------
__global__ __launch_bounds__(256) void upsample_k(const bf16* __restrict__ tb,
                                                  bf16* __restrict__ u) {
    const int b = blockIdx.z, i = blockIdx.y, j = blockIdx.x;
    const float si = 0.5f * i - 0.25f, sj = 0.5f * j - 0.25f;
    const int i0 = (int)floorf(si), j0 = (int)floorf(sj);
    const float wi = si - i0, wj = sj - j0;
    const int i0c = max(i0, 0), i1c = min(i0 + 1, 13);
    const int j0c = max(j0, 0), j1c = min(j0 + 1, 13);
    const bf16* base = tb + (long)b * 196 * CDIM;
    const long r00 = ((long)i0c * 14 + j0c) * CDIM, r01 = ((long)i0c * 14 + j1c) * CDIM;
    const long r10 = ((long)i1c * 14 + j0c) * CDIM, r11 = ((long)i1c * 14 + j1c) * CDIM;
    bf16* ur = u + ((long)(b * 28 + i) * 28 + j) * CDIM;
    const float w00 = (1.f - wi) * (1.f - wj), w01 = (1.f - wi) * wj;
    const float w10 = wi * (1.f - wj), w11 = wi * wj;
    for (int k = 0; k < 8; k++) {
        int cc = threadIdx.x + 256 * k;
        float v = w00 * (float)base[r00 + cc] + w01 * (float)base[r01 + cc] +
                  w10 * (float)base[r10 + cc] + w11 * (float)base[r11 + cc];
        ur[cc] = (bf16)v;
    }
}

// ---------------- deconv weight transform ----------------
__global__ __launch_bounds__(256) void wt_k(const float* __restrict__ dw,
                                            bf16* __restrict__ Wt) {
    const int ic = blockIdx.x * 256 + threadIdx.x;
    const int oc = blockIdx.y;
    const float* src = dw + ((long)ic * 1024 + oc) * 9;
#pragma unroll
    for (int r = 0; r < 3; r++)
#pragma unroll
        for (int s = 0; s < 3; s++) {
            int kh = 2 - r, kw = 2 - s;
            Wt[((long)(kh * 3 + kw) * 1024 + oc) * 2048 + ic] = (bf16)src[r * 3 + s];
        }
}

// ---------------- deconv scatter: r[g*1024+oc][b*784+p] (bf16) -> out[b][oc][82][82] ----------------
__global__ __launch_bounds__(256) void deconv_scatter_k(const bf16* __restrict__ r,
                                                        const float* __restrict__ db,
                                                        float* __restrict__ out) {
    const int blk = blockIdx.x;          // 4096 = b*1024 + oc
    const int b = blk >> 10, oc = blk & 1023;
    const float bias = db[oc];
    float* ob = out + (long)blk * 82 * 82;
    for (int e = threadIdx.x; e < 82 * 82; e += 256) {
        const int oh = e / 82, ow = e - oh * 82;
        const int mh = oh % 3, mw = ow % 3;
        const int kh = (mh == 0) ? 1 : ((mh == 1) ? 0 : 2);
        const int kw = (mw == 0) ? 1 : ((mw == 1) ? 0 : 2);
        const int ih = (oh - (1 - kh)) / 3;
        const int iw = (ow - (1 - kw)) / 3;
        const int g = kh * 3 + kw;
        ob[e] = (float)r[(long)(g * 1024 + oc) * 3136 + b * 784 + ih * 28 + iw] + bias;
    }
}

// =====================================================================
extern "C" void kernel_launch(void* const* d_in, const int* in_sizes, int n_in,
                              void* d_out, int out_size, void* d_ws, size_t ws_size,
                              hipStream_t stream) {
    const float* x        = (const float*)d_in[0];
    const float* w_fc1    = (const float*)d_in[1];
    const float* w1       = (const float*)d_in[2];
    const float* g1       = (const float*)d_in[3];
    const float* b1       = (const float*)d_in[4];
    const float* w2       = (const float*)d_in[5];
    const float* g2       = (const float*)d_in[6];
    const float* b2       = (const float*)d_in[7];
    const float* w3       = (const float*)d_in[8];
    const float* g3       = (const float*)d_in[9];
    const float* b3       = (const float*)d_in[10];
    const float* conv1_w  = (const float*)d_in[11];
    const float* conv1_b  = (const float*)d_in[12];
    const float* deconv_w = (const float*)d_in[13];
    const float* deconv_b = (const float*)d_in[14];
    float* out = (float*)d_out;

    // ---- workspace layout (bytes) ----
    char* W = (char*)d_ws;
    bf16* wb   = (bf16*)(W + 0);            // 4 x 2048x2048 bf16 = 33,554,432
    bf16* xb   = (bf16*)(W + 33554432);     // 6272x2048 bf16 (later: z)
    bf16* xbT  = (bf16*)(W + 59244544);     // 4 x 2048x1568 bf16 (later: zT)
    bf16* hb   = (bf16*)(W + 84934656);     // 6272x2048 bf16 (later: outN)
    bf16* lap  = (bf16*)(W + 110624768);    // 4 x 1568x1568 bf16 = 19,668,992
    bf16* tbuf = (bf16*)(W + 130293760);    // 4 x 196x2048 bf16 = 3,211,264
    bf16* ubuf = (bf16*)(W + 133505024);    // 4 x 784x2048 bf16 = 12,845,056
    bf16* Wt   = (bf16*)(W + 146350080);    // 9 x 1024x2048 bf16 = 37,748,736
    float* ybuf = (float*)(W + 184098816);  // 6272x2048 f32 = 51,380,224
    float* sbuf = (float*)(W + 184098816);  // s overlays y (dead before first y write)
    float* part = (float*)(W + 235479040);  // 8x4x1568 f32
    float* invc = (float*)(W + 235679744);  // 4x1568 f32
    // rbuf (bf16 now) overlays wb/xb region: dead by deconv time
    bf16* rbuf = (bf16*)(W + 0);            // 9216 x 3136 bf16 = 57,802,752
    bf16* zb = xb;    // reuse (xb dead after fc1 + transpose)
    bf16* zT = xbT;   // reuse
    bf16* outN = hb;  // reuse (hb dead after s GEMM)

    const long WMAT = (long)2048 * 2048;
    bf16* wb0 = wb, *wb1 = wb + WMAT, *wb2 = wb + 2 * WMAT, *wb3 = wb + 3 * WMAT;

    // ---- weight / input casts ----
    cast4_f32_bf16_k<<<dim3(4096, 4), 256, 0, stream>>>(w_fc1, w1, w2, w3, wb, WMAT);
    cast_f32_bf16_k<<<dim3(12544), 256, 0, stream>>>(x, xb, (long)6272 * 2048);
    wt_k<<<dim3(8, 1024), 256, 0, stream>>>(deconv_w, Wt);

    // xbT = per-batch transpose of xb: [1568,2048] -> [2048,1568]
    transpose_bf16_k<<<dim3(32, 25, 4), 256, 0, stream>>>(
        xb, xbT, N_NODES, CDIM, (long)N_NODES * CDIM, (long)N_NODES * CDIM);

    // ---- h = x @ w_fc1^T  (NT: M=6272,N=2048,K=2048) ----
    gemm_nt<bf16><<<dim3(49, 16, 1), 256, 0, stream>>>(
        xb, wb0, hb, 6272, 2048, 2048, 0, 0, 0);

    // ---- s = h h^T per batch (symmetric: 91 upper-tri tiles, mirrored) ----
    gemm_nt_sym<<<dim3(91, 1, 4), 256, 0, stream>>>(
        hb, sbuf, N_NODES, 2048,
        (long)N_NODES * 2048, (long)N_NODES * N_NODES);

    // ---- lap = 0.5*s^2/colsum + 0.5*I ----
    colsum_part_k<<<dim3(7, 8, 4), 256, 0, stream>>>(sbuf, part);
    colsum_comb_k<<<dim3(7, 4), 256, 0, stream>>>(part, invc);
    lap_build_k<<<dim3(7, N_NODES, 4), 256, 0, stream>>>(sbuf, invc, lap);

    // ---- 3x (lap matmul -> linear -> LN+leaky) ----
    const bf16* wlayer[3] = {wb1, wb2, wb3};
    const float* gl[3] = {g1, g2, g3};
    const float* bl[3] = {b1, b2, b3};
    for (int i = 0; i < 3; i++) {
        const bf16* prevT = (i == 0) ? xbT : zT;
        // outN = lap @ prev = NT(lap, prevT): M=1568, N=2048, K=1568, batched
        gemm_nt<bf16><<<dim3(13, 16, 4), 256, 0, stream>>>(
            lap, prevT, outN, N_NODES, CDIM, N_NODES,
            (long)N_NODES * N_NODES, (long)CDIM * N_NODES, (long)N_NODES * CDIM);
        // y = outN @ w^T  (M=6272, N=2048, K=2048)
        gemm_nt<float><<<dim3(49, 16, 1), 256, 0, stream>>>(
            outN, wlayer[i], ybuf, 6272, 2048, 2048, 0, 0, 0);
        // z = leaky(LN(y))
        ln_leaky_k<<<dim3(6272), 256, 0, stream>>>(ybuf, gl[i], bl[i], zb);
        if (i < 2) {
            transpose_bf16_k<<<dim3(32, 25, 4), 256, 0, stream>>>(
                zb, zT, N_NODES, CDIM, (long)N_NODES * CDIM, (long)N_NODES * CDIM);
        }
    }

    // ---- head ----
    conv1_k<<<dim3(8, 196, 4), 256, 0, stream>>>(zb, conv1_w, conv1_b, tbuf);
    upsample_k<<<dim3(28, 28, 4), 256, 0, stream>>>(tbuf, ubuf);
    // deconv as single GEMM: rbuf[g*1024+oc][b*784+pix] = Wt[9216,2048] x u[3136,2048]^T
    gemm_nt<bf16><<<dim3(72, 25, 1), 256, 0, stream>>>(
        Wt, ubuf, rbuf, 9216, 3136, 2048, 0, 0, 0);
    deconv_scatter_k<<<dim3(4096), 256, 0, stream>>>(rbuf, deconv_b, out);

    (void)in_sizes; (void)n_in; (void)out_size; (void)ws_size;
}